// Round 4
// baseline (26.142 us; speedup 1.0000x reference)
//
#include <hip/hip_runtime.h>

// SpectralLoss: mean over all 8x8 blocks of (T (x-y) T^T)^2 * W
// B=16, C=3, H=512, W=512 -> 196608 blocks. 2 threads per 8x8 block
// (output-column halves). Two-kernel deterministic reduction (no cross-XCD
// protocol -- R2's ticket scheme hit stale-visibility on replay).

#define WG 256
#define NWG 1536u                  // 1536*256 threads = 2 per 8x8 block
#define INV_N (1.0f/12582912.0f)   // 16*3*512*512

typedef float v4f __attribute__((ext_vector_type(4)));  // native vec for nontemporal

__global__ __launch_bounds__(WG) void spectral_partial(
    const float* __restrict__ x,
    const float* __restrict__ y,
    const float* __restrict__ Tm,
    const float* __restrict__ Wm,
    float* __restrict__ ws)
{
    const int tid  = threadIdx.x;
    const int gt   = blockIdx.x * WG + tid;
    const int p    = gt >> 1;            // 8x8-block id
    const int half = gt & 1;             // which 4 output columns
    const int img  = p >> 12;            // 4096 blocks per image plane
    const int rem  = p & 4095;
    const int hb   = rem >> 6;
    const int wb   = rem & 63;
    const int base = img * 262144 + hb * 4096 + wb * 8;

    // Full T: uniform addresses -> scalar loads/SGPRs (used in phase 2).
    float tT[8][8];
#pragma unroll
    for (int i = 0; i < 8; ++i) {
        float4 t0 = reinterpret_cast<const float4*>(Tm)[2*i];
        float4 t1 = reinterpret_cast<const float4*>(Tm)[2*i+1];
        tT[i][0]=t0.x; tT[i][1]=t0.y; tT[i][2]=t0.z; tT[i][3]=t0.w;
        tT[i][4]=t1.x; tT[i][5]=t1.y; tT[i][6]=t1.z; tT[i][7]=t1.w;
    }
    // The 4 T-rows for this thread's column half (lane-dependent -> VGPRs).
    float tl[4][8];
#pragma unroll
    for (int l = 0; l < 4; ++l) {
        const float* tr = Tm + (half*4 + l)*8;
        float4 t0 = reinterpret_cast<const float4*>(tr)[0];
        float4 t1 = reinterpret_cast<const float4*>(tr)[1];
        tl[l][0]=t0.x; tl[l][1]=t0.y; tl[l][2]=t0.z; tl[l][3]=t0.w;
        tl[l][4]=t1.x; tl[l][5]=t1.y; tl[l][6]=t1.z; tl[l][7]=t1.w;
    }

    // Phase 1: M[r][l] = sum_j D[r][j] * T[half*4+l][j], D = x - y streamed.
    float M[8][4];
#pragma unroll
    for (int r = 0; r < 8; ++r) {
        const v4f* xp = reinterpret_cast<const v4f*>(x + base + r*512);
        const v4f* yp = reinterpret_cast<const v4f*>(y + base + r*512);
        v4f a0 = __builtin_nontemporal_load(xp);
        v4f a1 = __builtin_nontemporal_load(xp + 1);
        v4f b0 = __builtin_nontemporal_load(yp);
        v4f b1 = __builtin_nontemporal_load(yp + 1);
        float row[8] = {a0.x-b0.x, a0.y-b0.y, a0.z-b0.z, a0.w-b0.w,
                        a1.x-b1.x, a1.y-b1.y, a1.z-b1.z, a1.w-b1.w};
#pragma unroll
        for (int l = 0; l < 4; ++l) {
            float acc = row[0]*tl[l][0];
#pragma unroll
            for (int j = 1; j < 8; ++j) acc += row[j]*tl[l][j];
            M[r][l] = acc;
        }
    }

    // Phase 2: s = sum_i sum_{l in half} W[i][l] * (sum_r T[i][r]*M[r][l])^2
    float s = 0.0f;
#pragma unroll
    for (int i = 0; i < 8; ++i) {
        float4 w4 = *reinterpret_cast<const float4*>(Wm + i*8 + half*4);
        float wr[4] = {w4.x, w4.y, w4.z, w4.w};
#pragma unroll
        for (int l = 0; l < 4; ++l) {
            float d = tT[i][0]*M[0][l];
#pragma unroll
            for (int r = 1; r < 8; ++r) d += tT[i][r]*M[r][l];
            s += wr[l]*d*d;
        }
    }

    // Deterministic workgroup reduction: wave shuffle + LDS across 4 waves.
#pragma unroll
    for (int off = 32; off > 0; off >>= 1) s += __shfl_down(s, off, 64);
    __shared__ float wsum[WG/64];
    if ((tid & 63) == 0) wsum[tid >> 6] = s;
    __syncthreads();
    if (tid == 0) ws[blockIdx.x] = wsum[0] + wsum[1] + wsum[2] + wsum[3];
}

__global__ __launch_bounds__(256) void spectral_reduce(
    const float* __restrict__ ws, float* __restrict__ out)
{
    const int tid = threadIdx.x;
    float s = 0.0f;
#pragma unroll
    for (int k = 0; k < 6; ++k) s += ws[tid + k*256];
#pragma unroll
    for (int off = 32; off > 0; off >>= 1) s += __shfl_down(s, off, 64);
    __shared__ float wsum[4];
    if ((tid & 63) == 0) wsum[tid >> 6] = s;
    __syncthreads();
    if (tid == 0) out[0] = (wsum[0]+wsum[1]+wsum[2]+wsum[3]) * INV_N;
}

extern "C" void kernel_launch(void* const* d_in, const int* in_sizes, int n_in,
                              void* d_out, int out_size, void* d_ws, size_t ws_size,
                              hipStream_t stream) {
    const float* x  = (const float*)d_in[0];   // input  (16,3,512,512) f32
    const float* y  = (const float*)d_in[1];   // target (16,3,512,512) f32
    const float* Tm = (const float*)d_in[2];   // 8x8 DCT
    const float* Wm = (const float*)d_in[3];   // 8x8 weight
    float* ws  = (float*)d_ws;                 // 1536 partials
    float* out = (float*)d_out;                // scalar f32

    spectral_partial<<<NWG, WG, 0, stream>>>(x, y, Tm, Wm, ws);
    spectral_reduce<<<1, 256, 0, stream>>>(ws, out);
}